// Round 4
// baseline (1522.540 us; speedup 1.0000x reference)
//
#include <hip/hip_runtime.h>
#include <hip/hip_bf16.h>

#define Hh   128
#define FH   512
#define Lz   64
#define Tt   12
#define NFf  16

// ---------------- dtype detection: are float tensors bf16 or f32? ----------------
__global__ void detect_k(const unsigned short* __restrict__ zraw, int* __restrict__ flag)
{
    __shared__ int cnt;
    if (threadIdx.x == 0) cnt = 0;
    __syncthreads();
    unsigned short u = zraw[threadIdx.x];
    int e = (u >> 7) & 0xFF;                       // bf16 exponent field
    int plausible = (e == 0) || (e >= 107 && e <= 131);  // 0/denorm or |x| in [2^-20, 16]
    if (plausible) atomicAdd(&cnt, 1);
    __syncthreads();
    if (threadIdx.x == 0) *flag = (cnt >= 250) ? 1 : 0;   // 1 => bf16 storage
}

// ---------------- edge-layout detection: int32 or int64 storage? ----------------
__global__ void detect_edge_k(const unsigned int* __restrict__ w, int Nn, int* __restrict__ eflag)
{
    __shared__ int oddnz, evenbad;
    if (threadIdx.x == 0) { oddnz = 0; evenbad = 0; }
    __syncthreads();
    unsigned int v = w[threadIdx.x];
    if (threadIdx.x & 1) { if (v != 0) atomicAdd(&oddnz, 1); }
    else                 { if (v >= (unsigned)Nn) atomicAdd(&evenbad, 1); }
    __syncthreads();
    if (threadIdx.x == 0) *eflag = (oddnz == 0 && evenbad == 0) ? 1 : 0;  // 1 => int64
}

__device__ __forceinline__ float ldval(const void* p, long i, int isbf16)
{
    return isbf16 ? __bfloat162float(((const __hip_bfloat16*)p)[i])
                  : ((const float*)p)[i];
}

__device__ __forceinline__ int edge_at(const void* p, long i, int is64)
{
    return is64 ? (int)(((const long long*)p)[i]) : ((const int*)p)[i];
}

// ---------------- graph prep ----------------

__global__ void node_mask_k(const unsigned char* __restrict__ xm, float* __restrict__ mask, int Nn)
{
    int n = blockIdx.x * 256 + threadIdx.x;
    if (n >= Nn) return;
    const unsigned int* p = (const unsigned int*)(xm + (size_t)n * 192);
    unsigned int o = 0;
#pragma unroll
    for (int i = 0; i < 48; ++i) o |= p[i];
    mask[n] = o ? 1.0f : 0.0f;
}

__global__ void deg_count_k(const void* __restrict__ edge, int* __restrict__ degi, int E, int Nn,
                            const int* __restrict__ eflag)
{
    int is64 = *eflag;
    int e = blockIdx.x * 256 + threadIdx.x;
    if (e >= E) return;
    int d = edge_at(edge, (long)E + e, is64);
    d = d < 0 ? 0 : (d >= Nn ? Nn - 1 : d);
    atomicAdd(&degi[d], 1);
}

__global__ void dinv_k(const int* __restrict__ degi, float* __restrict__ dinv, int Nn)
{
    int n = blockIdx.x * 256 + threadIdx.x;
    if (n >= Nn) return;
    dinv[n] = rsqrtf((float)(degi[n] + 1)); // +1 self loop
}

__global__ void scan_k(const int* __restrict__ degi, int* __restrict__ rowptr, int Nn)
{
    __shared__ int buf[1024];
    __shared__ int carry;
    int tid = threadIdx.x;
    if (tid == 0) carry = 0;
    __syncthreads();
    for (int base = 0; base < Nn; base += 1024) {
        int i = base + tid;
        buf[tid] = (i < Nn) ? degi[i] : 0;
        __syncthreads();
        for (int off = 1; off < 1024; off <<= 1) {
            int x = (tid >= off) ? buf[tid - off] : 0;
            __syncthreads();
            buf[tid] += x;
            __syncthreads();
        }
        if (i < Nn) rowptr[i + 1] = carry + buf[tid];
        __syncthreads();
        if (tid == 1023) carry += buf[1023];
        __syncthreads();
    }
    if (tid == 0) rowptr[0] = 0;
}

__global__ void csr_fill_k(const void* __restrict__ edge,
                           const float* __restrict__ dinv, const int* __restrict__ rowptr,
                           int* __restrict__ cursor, int* __restrict__ colsrc,
                           float* __restrict__ wnorm, int E, int Nn,
                           const int* __restrict__ eflag)
{
    int is64 = *eflag;
    int e = blockIdx.x * 256 + threadIdx.x;
    if (e >= E) return;
    int s = edge_at(edge, e, is64);
    int d = edge_at(edge, (long)E + e, is64);
    s = s < 0 ? 0 : (s >= Nn ? Nn - 1 : s);
    d = d < 0 ? 0 : (d >= Nn ? Nn - 1 : d);
    int pos = rowptr[d] + atomicAdd(&cursor[d], 1);
    colsrc[pos] = s;
    wnorm[pos]  = dinv[s] * dinv[d];
}

// ---------------- weight prep (bf16/f32 -> f32, transpose) ----------------

__global__ void prep_weights_k(const void* __restrict__ Wih, const void* __restrict__ Whh,
                               const void* __restrict__ Wg,  const void* __restrict__ W3,
                               const void* __restrict__ Wf2,
                               const void* __restrict__ bf2, const void* __restrict__ bih,
                               const void* __restrict__ bhh, const void* __restrict__ bg,
                               const void* __restrict__ b3,
                               float* __restrict__ WihT, float* __restrict__ WhhT, float* __restrict__ WgF,
                               float* __restrict__ W3F,  float* __restrict__ Wf2F,
                               float* __restrict__ bf2F, float* __restrict__ bihF, float* __restrict__ bhhF,
                               float* __restrict__ bgF,  float* __restrict__ b3F,
                               const int* __restrict__ flag)
{
    int fl = *flag;
    int i = blockIdx.x * 256 + threadIdx.x;
    if (i < FH * Hh) {          // 65536: W_ih / W_hh are [4H][H] row-major -> [H][4H]
        int j = i >> 7, k = i & 127;
        WihT[k * FH + j] = ldval(Wih, i, fl);
        WhhT[k * FH + j] = ldval(Whh, i, fl);
    }
    if (i < Hh * Hh)  WgF[i]  = ldval(Wg, i, fl);
    if (i < Lz * Hh)  Wf2F[i] = ldval(Wf2, i, fl);
    if (i < Hh * NFf) W3F[i]  = ldval(W3, i, fl);
    if (i < FH) { bihF[i] = ldval(bih, i, fl); bhhF[i] = ldval(bhh, i, fl); }
    if (i < Hh) { bf2F[i] = ldval(bf2, i, fl); bgF[i]  = ldval(bg, i, fl); }
    if (i < NFf) b3F[i] = ldval(b3, i, fl);
}

// ---------------- fc2: hd = z @ W_fc2 + b ----------------

__global__ void fc2_k(const void* __restrict__ z, const float* __restrict__ B,
                      const float* __restrict__ bias, float* __restrict__ C, int Nn,
                      const int* __restrict__ flag)
{
    const int NB = 16;
    __shared__ float As[NB][Lz];
    int fl = *flag;
    int n0 = blockIdx.x * NB;
    int tid = threadIdx.x; // 128 threads
    for (int idx = tid; idx < NB * Lz; idx += Hh) {
        int r = idx >> 6, c = idx & 63;
        int n = n0 + r;
        As[r][c] = (n < Nn) ? ldval(z, (long)n * Lz + c, fl) : 0.f;
    }
    __syncthreads();
    float acc[NB];
#pragma unroll
    for (int i = 0; i < NB; ++i) acc[i] = 0.f;
#pragma unroll 4
    for (int k = 0; k < Lz; ++k) {
        float w = B[k * Hh + tid];
#pragma unroll
        for (int i = 0; i < NB; ++i) acc[i] += As[i][k] * w;
    }
    float bb = bias[tid];
    for (int i = 0; i < NB; ++i) {
        int n = n0 + i;
        if (n < Nn) C[(size_t)n * Hh + tid] = acc[i] + bb;
    }
}

// ---------------- generic row-block GEMM: C[n,j] = sum_k A[n,k] B[k,j] (+bias) ----------------

template<int J, int K, int NB>
__global__ void gemm_k(const float* __restrict__ A, const float* __restrict__ B,
                       const float* __restrict__ bias, float* __restrict__ C, int Nn)
{
    __shared__ float As[NB][K];
    int n0 = blockIdx.x * NB;
    int tid = threadIdx.x; // J threads
    for (int idx = tid; idx < NB * K; idx += J) {
        int r = idx / K, c = idx % K;
        int n = n0 + r;
        As[r][c] = (n < Nn) ? A[(size_t)n * K + c] : 0.f;
    }
    __syncthreads();
    float acc[NB];
#pragma unroll
    for (int i = 0; i < NB; ++i) acc[i] = 0.f;
#pragma unroll 4
    for (int k = 0; k < K; ++k) {
        float w = B[k * J + tid];
#pragma unroll
        for (int i = 0; i < NB; ++i) acc[i] += As[i][k] * w;
    }
    float bb = bias ? bias[tid] : 0.f;
    for (int i = 0; i < NB; ++i) {
        int n = n0 + i;
        if (n < Nn) C[(size_t)n * J + tid] = acc[i] + bb;
    }
}

// ---------------- fused LSTM step ----------------

__device__ __forceinline__ float sigf(float x) { return 1.0f / (1.0f + __expf(-x)); }

__global__ void lstm_step_k(const float* __restrict__ xproj, const float* __restrict__ WhhT,
                            const float* __restrict__ bhhF, float* __restrict__ h,
                            float* __restrict__ c, const float* __restrict__ mask,
                            float* __restrict__ hm, int Nn)
{
    const int NB = 16;
    __shared__ float Hs[NB][Hh];
    __shared__ float Gs[NB][FH];
    int n0 = blockIdx.x * NB;
    int tid = threadIdx.x; // 512 threads
    for (int idx = tid; idx < NB * Hh; idx += FH) {
        int r = idx >> 7, cc = idx & 127;
        int n = n0 + r;
        Hs[r][cc] = (n < Nn) ? h[(size_t)n * Hh + cc] : 0.f;
    }
    __syncthreads();
    float acc[NB];
#pragma unroll
    for (int i = 0; i < NB; ++i) acc[i] = 0.f;
#pragma unroll 4
    for (int k = 0; k < Hh; ++k) {
        float w = WhhT[k * FH + tid];
#pragma unroll
        for (int i = 0; i < NB; ++i) acc[i] += Hs[i][k] * w;
    }
    float bb = bhhF[tid];
#pragma unroll
    for (int i = 0; i < NB; ++i) {
        int n = n0 + i;
        Gs[i][tid] = acc[i] + bb + ((n < Nn) ? xproj[(size_t)n * FH + tid] : 0.f);
    }
    __syncthreads();
    // pointwise gates: i,f,g,o at offsets 0/128/256/384
    for (int idx = tid; idx < NB * Hh; idx += FH) {
        int r = idx >> 7, jj = idx & 127;
        int n = n0 + r;
        if (n >= Nn) continue;
        float gi = Gs[r][jj];
        float gf = Gs[r][jj + 128];
        float gg = Gs[r][jj + 256];
        float go = Gs[r][jj + 384];
        size_t off = (size_t)n * Hh + jj;
        float cn = sigf(gf) * c[off] + sigf(gi) * tanhf(gg);
        float hn = sigf(go) * tanhf(cn);
        c[off] = cn;
        h[off] = hn;
        hm[off] = hn * mask[n];
    }
}

// ---------------- GCN aggregate (CSR by dst, no atomics) ----------------

__global__ void gcn_agg_k(const float* __restrict__ xw, const int* __restrict__ rowptr,
                          const int* __restrict__ colsrc, const float* __restrict__ wnorm,
                          const float* __restrict__ dinv, float* __restrict__ agg, int Nn)
{
    int hcol = threadIdx.x;                  // 0..127
    int n = blockIdx.x * blockDim.y + threadIdx.y;
    if (n >= Nn) return;
    float dv = dinv[n];
    float a = xw[(size_t)n * Hh + hcol] * dv * dv;  // self loop
    int s0 = rowptr[n], s1 = rowptr[n + 1];
    for (int e = s0; e < s1; ++e) {
        int s = colsrc[e];
        float w = wnorm[e];
        a += xw[(size_t)s * Hh + hcol] * w;
    }
    agg[(size_t)n * Hh + hcol] = a;
}

// ---------------- fc3 -> out (f32) ----------------

__global__ void fc3_out_k(const float* __restrict__ agg, const float* __restrict__ bgF,
                          const float* __restrict__ W3F, const float* __restrict__ b3F,
                          float* __restrict__ out, int t, int Nn)
{
    const int NB = 16; // 256 threads = 16 nodes x 16 feats
    __shared__ float As[NB][Hh];
    int n0 = blockIdx.x * NB;
    int tid = threadIdx.x;
    for (int idx = tid; idx < NB * Hh; idx += 256) {
        int r = idx >> 7, cc = idx & 127;
        int n = n0 + r;
        As[r][cc] = (n < Nn) ? (agg[(size_t)n * Hh + cc] + bgF[cc]) : 0.f;
    }
    __syncthreads();
    int r = tid >> 4, f = tid & 15;
    int n = n0 + r;
    if (n >= Nn) return;
    float a = b3F[f];
#pragma unroll 4
    for (int k = 0; k < Hh; ++k) a += As[r][k] * W3F[k * NFf + f];
    out[((size_t)n * Tt + t) * NFf + f] = a;
}

// ---------------- launcher ----------------

extern "C" void kernel_launch(void* const* d_in, const int* in_sizes, int n_in,
                              void* d_out, int out_size, void* d_ws, size_t ws_size,
                              hipStream_t stream)
{
    const void*           z     = d_in[0];
    const void*           edge  = d_in[1];
    const unsigned char*  xmask = (const unsigned char*)d_in[2];
    const void* W_fc2 = d_in[3];
    const void* b_fc2 = d_in[4];
    const void* W_ih  = d_in[5];
    const void* W_hh  = d_in[6];
    const void* b_ih  = d_in[7];
    const void* b_hh  = d_in[8];
    const void* W_gcn = d_in[9];
    const void* b_gcn = d_in[10];
    const void* W_fc3 = d_in[11];
    const void* b_fc3 = d_in[12];
    float* out = (float*)d_out;

    const int N = in_sizes[0] / Lz;   // 10000
    const int E = in_sizes[1] / 2;    // 160000

    // workspace carve (256B aligned)
    char* w = (char*)d_ws;
    auto alloc = [&](size_t bytes) { char* p = w; w += (bytes + 255) & ~(size_t)255; return p; };
    float* h_buf  = (float*)alloc((size_t)N * Hh * 4);
    float* c_buf  = (float*)alloc((size_t)N * Hh * 4);
    float* hm_buf = (float*)alloc((size_t)N * Hh * 4);
    float* xproj  = (float*)alloc((size_t)N * FH * 4);
    float* xw     = (float*)alloc((size_t)N * Hh * 4);
    float* agg    = (float*)alloc((size_t)N * Hh * 4);
    float* mask   = (float*)alloc((size_t)N * 4);
    float* dinv   = (float*)alloc((size_t)N * 4);
    int*   degi   = (int*)alloc((size_t)N * 4);
    int*   rowptr = (int*)alloc((size_t)(N + 1) * 4);
    int*   cursor = (int*)alloc((size_t)N * 4);
    int*   colsrc = (int*)alloc((size_t)E * 4);
    float* wnorm  = (float*)alloc((size_t)E * 4);
    float* WihT   = (float*)alloc((size_t)FH * Hh * 4);
    float* WhhT   = (float*)alloc((size_t)FH * Hh * 4);
    float* WgF    = (float*)alloc((size_t)Hh * Hh * 4);
    float* W3F    = (float*)alloc((size_t)Hh * NFf * 4);
    float* Wf2F   = (float*)alloc((size_t)Lz * Hh * 4);
    float* bf2F   = (float*)alloc(Hh * 4);
    float* bihF   = (float*)alloc(FH * 4);
    float* bhhF   = (float*)alloc(FH * 4);
    float* bgF    = (float*)alloc(Hh * 4);
    float* b3F    = (float*)alloc(NFf * 4);
    int*   dflag  = (int*)alloc(256);
    int*   eflag  = (int*)alloc(256);

    hipMemsetAsync(degi,   0, (size_t)N * 4, stream);
    hipMemsetAsync(cursor, 0, (size_t)N * 4, stream);
    hipMemsetAsync(c_buf,  0, (size_t)N * Hh * 4, stream);

    const int b256n = (N + 255) / 256;
    const int b256e = (E + 255) / 256;
    const int nb16  = (N + 15) / 16;

    detect_k<<<1, 256, 0, stream>>>((const unsigned short*)z, dflag);
    detect_edge_k<<<1, 512, 0, stream>>>((const unsigned int*)edge, N, eflag);
    node_mask_k<<<b256n, 256, 0, stream>>>(xmask, mask, N);
    deg_count_k<<<b256e, 256, 0, stream>>>(edge, degi, E, N, eflag);
    dinv_k<<<b256n, 256, 0, stream>>>(degi, dinv, N);
    scan_k<<<1, 1024, 0, stream>>>(degi, rowptr, N);
    csr_fill_k<<<b256e, 256, 0, stream>>>(edge, dinv, rowptr, cursor, colsrc, wnorm, E, N, eflag);
    prep_weights_k<<<(FH * Hh + 255) / 256, 256, 0, stream>>>(
        W_ih, W_hh, W_gcn, W_fc3, W_fc2, b_fc2, b_ih, b_hh, b_gcn, b_fc3,
        WihT, WhhT, WgF, W3F, Wf2F, bf2F, bihF, bhhF, bgF, b3F, dflag);

    // hd -> h_buf
    fc2_k<<<nb16, Hh, 0, stream>>>(z, Wf2F, bf2F, h_buf, N, dflag);
    // x_proj = hd @ W_ih^T + b_ih (input constant over time)
    gemm_k<FH, Hh, 16><<<nb16, FH, 0, stream>>>(h_buf, WihT, bihF, xproj, N);

    for (int t = 0; t < Tt; ++t) {
        lstm_step_k<<<nb16, FH, 0, stream>>>(xproj, WhhT, bhhF, h_buf, c_buf, mask, hm_buf, N);
        gemm_k<Hh, Hh, 16><<<nb16, Hh, 0, stream>>>(hm_buf, WgF, nullptr, xw, N);
        dim3 aggblk(Hh, 4);
        gcn_agg_k<<<(N + 3) / 4, aggblk, 0, stream>>>(xw, rowptr, colsrc, wnorm, dinv, agg, N);
        fc3_out_k<<<nb16, 256, 0, stream>>>(agg, bgF, W3F, b3F, out, t, N);
    }
}

// Round 5
// 1003.304 us; speedup vs baseline: 1.5175x; 1.5175x over previous
//
#include <hip/hip_runtime.h>
#include <hip/hip_bf16.h>

#define Hh   128
#define FH   512
#define Lz   64
#define Tt   12
#define NFf  16

__device__ __forceinline__ float sigf(float x) { return 1.0f / (1.0f + __expf(-x)); }

// ---------------- graph prep ----------------

__global__ void node_mask_k(const unsigned char* __restrict__ xm, float* __restrict__ mask, int Nn)
{
    int n = blockIdx.x * 256 + threadIdx.x;
    if (n >= Nn) return;
    const unsigned int* p = (const unsigned int*)(xm + (size_t)n * 192);
    unsigned int o = 0;
#pragma unroll
    for (int i = 0; i < 48; ++i) o |= p[i];
    mask[n] = o ? 1.0f : 0.0f;
}

__global__ void deg_count_k(const int* __restrict__ dst, int* __restrict__ degi, int E, int Nn)
{
    int e = blockIdx.x * 256 + threadIdx.x;
    if (e >= E) return;
    int d = dst[e]; d = d < 0 ? 0 : (d >= Nn ? Nn - 1 : d);
    atomicAdd(&degi[d], 1);
}

__global__ void dinv_k(const int* __restrict__ degi, float* __restrict__ dinv, int Nn)
{
    int n = blockIdx.x * 256 + threadIdx.x;
    if (n >= Nn) return;
    dinv[n] = rsqrtf((float)(degi[n] + 1)); // +1 self loop
}

// single-block scan, wave-shuffle based (few barriers)
__global__ void scan_k(const int* __restrict__ degi, int* __restrict__ rowptr, int Nn)
{
    __shared__ int wsum[16];
    __shared__ int carry;
    int tid = threadIdx.x;           // 1024
    int lane = tid & 63, wid = tid >> 6;
    if (tid == 0) carry = 0;
    __syncthreads();
    for (int base = 0; base < Nn; base += 1024) {
        int i = base + tid;
        int v = (i < Nn) ? degi[i] : 0;
        int x = v;
#pragma unroll
        for (int off = 1; off < 64; off <<= 1) {
            int y = __shfl_up(x, off, 64);
            if (lane >= off) x += y;
        }
        if (lane == 63) wsum[wid] = x;
        __syncthreads();
        if (wid == 0) {
            int s = (lane < 16) ? wsum[lane] : 0;
#pragma unroll
            for (int off = 1; off < 16; off <<= 1) {
                int y = __shfl_up(s, off, 64);
                if (lane >= off) s += y;
            }
            if (lane < 16) wsum[lane] = s;
        }
        __syncthreads();
        int woff = (wid > 0) ? wsum[wid - 1] : 0;
        int inc = carry + woff + x;
        if (i < Nn) rowptr[i + 1] = inc;
        __syncthreads();
        if (tid == 1023) carry = inc;
        __syncthreads();
    }
    if (tid == 0) rowptr[0] = 0;
}

__global__ void csr_fill_k(const int* __restrict__ src, const int* __restrict__ dst,
                           const float* __restrict__ dinv, const int* __restrict__ rowptr,
                           int* __restrict__ cursor, int* __restrict__ colsrc,
                           float* __restrict__ wnorm, int E, int Nn)
{
    int e = blockIdx.x * 256 + threadIdx.x;
    if (e >= E) return;
    int s = src[e]; s = s < 0 ? 0 : (s >= Nn ? Nn - 1 : s);
    int d = dst[e]; d = d < 0 ? 0 : (d >= Nn ? Nn - 1 : d);
    int pos = rowptr[d] + atomicAdd(&cursor[d], 1);
    colsrc[pos] = s;
    wnorm[pos]  = dinv[s] * dinv[d];
}

// ---------------- weight fusion ----------------

// WhhT[k][j] = W_hh[j][k]
__global__ void whhT_prep_k(const float* __restrict__ Whh, float* __restrict__ WhhT)
{
    int i = blockIdx.x * 256 + threadIdx.x;
    if (i >= FH * Hh) return;
    int j = i >> 7, k = i & 127;
    WhhT[k * FH + j] = Whh[i];
}

// Wz[m][j] = sum_k Wf2[m][k] * Wih[j][k]   (m<64, j<512)
// bz[j]    = sum_k bf2[k]  * Wih[j][k] + bih[j]
__global__ void fuse_in_k(const float* __restrict__ Wf2, const float* __restrict__ Wih,
                          const float* __restrict__ bf2, const float* __restrict__ bih,
                          float* __restrict__ Wz, float* __restrict__ bz)
{
    int gid = blockIdx.x * 256 + threadIdx.x;
    if (gid < Lz * FH) {
        int m = gid >> 9, j = gid & 511;
        const float* a = Wf2 + m * Hh;
        const float* b = Wih + j * Hh;
        float s = 0.f;
#pragma unroll 4
        for (int k = 0; k < Hh; ++k) s += a[k] * b[k];
        Wz[m * FH + j] = s;
    } else if (gid < Lz * FH + FH) {
        int j = gid - Lz * FH;
        const float* b = Wih + j * Hh;
        float s = bih[j];
#pragma unroll 4
        for (int k = 0; k < Hh; ++k) s += bf2[k] * b[k];
        bz[j] = s;
    }
}

// WcT[f][k] = sum_h Wg[k][h] * W3[h][f]  ;  bc[f] = sum_h bg[h]*W3[h][f] + b3[f]
__global__ void fuse_gcn_k(const float* __restrict__ Wg, const float* __restrict__ W3,
                           const float* __restrict__ bg, const float* __restrict__ b3,
                           float* __restrict__ WcT, float* __restrict__ bc)
{
    int gid = blockIdx.x * 256 + threadIdx.x;
    if (gid < Hh * NFf) {
        int f = gid >> 7, k = gid & 127;
        const float* a = Wg + k * Hh;
        float s = 0.f;
#pragma unroll 4
        for (int h = 0; h < Hh; ++h) s += a[h] * W3[h * NFf + f];
        WcT[f * Hh + k] = s;
    } else if (gid < Hh * NFf + NFf) {
        int f = gid - Hh * NFf;
        float s = b3[f];
#pragma unroll 4
        for (int h = 0; h < Hh; ++h) s += bg[h] * W3[h * NFf + f];
        bc[f] = s;
    }
}

// ---------------- fc2: h0 = z @ W_fc2 + b ----------------

__global__ __launch_bounds__(128) void fc2_k(const float* __restrict__ z, const float* __restrict__ B,
                                             const float* __restrict__ bias, float* __restrict__ C, int Nn)
{
    __shared__ float As[16][Lz];
    int n0 = blockIdx.x * 16;
    int tid = threadIdx.x; // 128
    for (int idx = tid; idx < 16 * Lz; idx += 128) {
        int r = idx >> 6, c = idx & 63;
        int n = n0 + r;
        As[r][c] = (n < Nn) ? z[(size_t)n * Lz + c] : 0.f;
    }
    __syncthreads();
    float acc[16];
#pragma unroll
    for (int i = 0; i < 16; ++i) acc[i] = 0.f;
    for (int k = 0; k < Lz; k += 2) {
        float w0 = B[k * Hh + tid];
        float w1 = B[(k + 1) * Hh + tid];
#pragma unroll
        for (int i = 0; i < 16; ++i) {
            float2 a = *(const float2*)&As[i][k];
            acc[i] += a.x * w0 + a.y * w1;
        }
    }
    float bb = bias[tid];
    for (int i = 0; i < 16; ++i) {
        int n = n0 + i;
        if (n < Nn) C[(size_t)n * Hh + tid] = acc[i] + bb;
    }
}

// ---------------- xproj = z @ Wz + bz  (K=64, cols=512) ----------------

__global__ __launch_bounds__(128) void xproj_k(const float* __restrict__ A, const float* __restrict__ B,
                                               const float* __restrict__ bias, float* __restrict__ C, int Nn)
{
    __shared__ float As[16][Lz];
    int n0 = blockIdx.x * 16;
    int j = threadIdx.x; // 128
    for (int idx = j; idx < 16 * Lz; idx += 128) {
        int r = idx >> 6, c = idx & 63;
        int n = n0 + r;
        As[r][c] = (n < Nn) ? A[(size_t)n * Lz + c] : 0.f;
    }
    __syncthreads();
    float acc[16][4];
#pragma unroll
    for (int r = 0; r < 16; ++r)
#pragma unroll
        for (int q = 0; q < 4; ++q) acc[r][q] = 0.f;
    for (int k0 = 0; k0 < Lz; k0 += 2) {
        float b0[4], b1[4];
#pragma unroll
        for (int q = 0; q < 4; ++q) {
            b0[q] = B[k0 * FH + q * 128 + j];
            b1[q] = B[(k0 + 1) * FH + q * 128 + j];
        }
#pragma unroll
        for (int r = 0; r < 16; ++r) {
            float2 a = *(const float2*)&As[r][k0];
#pragma unroll
            for (int q = 0; q < 4; ++q) acc[r][q] += a.x * b0[q] + a.y * b1[q];
        }
    }
    float bq[4];
#pragma unroll
    for (int q = 0; q < 4; ++q) bq[q] = bias[q * 128 + j];
    for (int r = 0; r < 16; ++r) {
        int n = n0 + r;
        if (n >= Nn) break;
#pragma unroll
        for (int q = 0; q < 4; ++q) C[(size_t)n * FH + q * 128 + j] = acc[r][q] + bq[q];
    }
}

// ---------------- fused LSTM step: gates GEMM + pointwise + pw slice ----------------
// 128 threads, 16 rows/block. Thread j owns gate cols {j, j+128, j+256, j+384}.
// After pointwise, hm is staged in LDS and pw[n][t][:16] = hm @ Wc computed in-block.

__global__ __launch_bounds__(128) void lstm_fused_k(
    const float* __restrict__ xproj, const float* __restrict__ WhhT,
    const float* __restrict__ bhh, float* __restrict__ h,
    float* __restrict__ c, const float* __restrict__ mask,
    const float* __restrict__ WcT, float* __restrict__ pw,
    int t, int Nn)
{
    __shared__ float As[16][Hh];
    int n0 = blockIdx.x * 16;
    int j = threadIdx.x;
    // stage h rows (coalesced: iteration i loads row i col j)
#pragma unroll
    for (int i = 0; i < 16; ++i) {
        int n = n0 + i;
        As[i][j] = (n < Nn) ? h[(size_t)n * Hh + j] : 0.f;
    }
    __syncthreads();

    float acc[16][4];
#pragma unroll
    for (int r = 0; r < 16; ++r)
#pragma unroll
        for (int q = 0; q < 4; ++q) acc[r][q] = 0.f;

    const float* Bp = WhhT + j;
    for (int k0 = 0; k0 < Hh; k0 += 2) {
        float b0[4], b1[4];
#pragma unroll
        for (int q = 0; q < 4; ++q) {
            b0[q] = Bp[k0 * FH + q * 128];
            b1[q] = Bp[(k0 + 1) * FH + q * 128];
        }
#pragma unroll
        for (int r = 0; r < 16; ++r) {
            float2 a = *(const float2*)&As[r][k0];
#pragma unroll
            for (int q = 0; q < 4; ++q) acc[r][q] += a.x * b0[q] + a.y * b1[q];
        }
    }
    __syncthreads();   // done reading As; will overwrite with hm

    float bq[4];
#pragma unroll
    for (int q = 0; q < 4; ++q) bq[q] = bhh[q * 128 + j];

#pragma unroll
    for (int r = 0; r < 16; ++r) {
        int n = n0 + r;
        float hmv = 0.f;
        if (n < Nn) {
            const float* xp = xproj + (size_t)n * FH;
            float gi = acc[r][0] + bq[0] + xp[j];
            float gf = acc[r][1] + bq[1] + xp[128 + j];
            float gg = acc[r][2] + bq[2] + xp[256 + j];
            float go = acc[r][3] + bq[3] + xp[384 + j];
            size_t off = (size_t)n * Hh + j;
            float cn = sigf(gf) * c[off] + sigf(gi) * tanhf(gg);
            float hn = sigf(go) * tanhf(cn);
            c[off] = cn;
            h[off] = hn;
            hmv = hn * mask[n];
        }
        As[r][j] = hmv;
    }
    __syncthreads();

    // pw: 256 outputs (16 rows x 16 f), 2 per thread
#pragma unroll
    for (int s = 0; s < 2; ++s) {
        int idx = j + s * 128;
        int r2 = idx >> 4, f = idx & 15;
        const float* wf = WcT + f * Hh;
        float a = 0.f;
#pragma unroll
        for (int k0 = 0; k0 < Hh; k0 += 4) {
            float4 av = *(const float4*)&As[r2][k0];
            float4 bv = *(const float4*)&wf[k0];
            a += av.x * bv.x + av.y * bv.y + av.z * bv.z + av.w * bv.w;
        }
        int n = n0 + r2;
        if (n < Nn) pw[((size_t)n * Tt + t) * NFf + f] = a;
    }
}

// ---------------- aggregate + bias -> out  (per dst node, all t,f at once) ----------------

__global__ __launch_bounds__(256) void agg_out_k(
    const float* __restrict__ pw, const int* __restrict__ rowptr,
    const int* __restrict__ colsrc, const float* __restrict__ wnorm,
    const float* __restrict__ dinv, const float* __restrict__ bc,
    float* __restrict__ out, int Nn)
{
    int lane = threadIdx.x & 63;
    int n = blockIdx.x * 4 + (threadIdx.x >> 6);
    if (n >= Nn) return;
    float dv = dinv[n];
    float sw = dv * dv;
    const float* pwn = pw + (size_t)n * 192;
    float a0 = pwn[lane] * sw;
    float a1 = pwn[64 + lane] * sw;
    float a2 = pwn[128 + lane] * sw;
    int s0 = rowptr[n], s1 = rowptr[n + 1];
    for (int e = s0; e < s1; ++e) {
        int s = colsrc[e];
        float w = wnorm[e];
        const float* ps = pw + (size_t)s * 192;
        a0 += ps[lane] * w;
        a1 += ps[64 + lane] * w;
        a2 += ps[128 + lane] * w;
    }
    float bcv = bc[lane & 15];
    float* on = out + (size_t)n * 192;
    on[lane]       = a0 + bcv;
    on[64 + lane]  = a1 + bcv;
    on[128 + lane] = a2 + bcv;
}

// ---------------- launcher ----------------

extern "C" void kernel_launch(void* const* d_in, const int* in_sizes, int n_in,
                              void* d_out, int out_size, void* d_ws, size_t ws_size,
                              hipStream_t stream)
{
    const float* z     = (const float*)d_in[0];
    const int*   edge  = (const int*)d_in[1];
    const unsigned char* xmask = (const unsigned char*)d_in[2];
    const float* W_fc2 = (const float*)d_in[3];
    const float* b_fc2 = (const float*)d_in[4];
    const float* W_ih  = (const float*)d_in[5];
    const float* W_hh  = (const float*)d_in[6];
    const float* b_ih  = (const float*)d_in[7];
    const float* b_hh  = (const float*)d_in[8];
    const float* W_gcn = (const float*)d_in[9];
    const float* b_gcn = (const float*)d_in[10];
    const float* W_fc3 = (const float*)d_in[11];
    const float* b_fc3 = (const float*)d_in[12];
    float* out = (float*)d_out;

    const int N = in_sizes[0] / Lz;   // 10000
    const int E = in_sizes[1] / 2;    // 160000
    const int* esrc = edge;
    const int* edst = edge + E;

    char* w = (char*)d_ws;
    auto alloc = [&](size_t bytes) { char* p = w; w += (bytes + 255) & ~(size_t)255; return p; };
    float* h_buf  = (float*)alloc((size_t)N * Hh * 4);
    float* c_buf  = (float*)alloc((size_t)N * Hh * 4);
    float* xproj  = (float*)alloc((size_t)N * FH * 4);
    float* pw     = (float*)alloc((size_t)N * Tt * NFf * 4);
    float* mask   = (float*)alloc((size_t)N * 4);
    float* dinv   = (float*)alloc((size_t)N * 4);
    int*   degi   = (int*)alloc((size_t)N * 4);
    int*   rowptr = (int*)alloc((size_t)(N + 1) * 4);
    int*   cursor = (int*)alloc((size_t)N * 4);
    int*   colsrc = (int*)alloc((size_t)E * 4);
    float* wnorm  = (float*)alloc((size_t)E * 4);
    float* WhhT   = (float*)alloc((size_t)FH * Hh * 4);
    float* Wz     = (float*)alloc((size_t)Lz * FH * 4);
    float* bz     = (float*)alloc(FH * 4);
    float* WcT    = (float*)alloc((size_t)NFf * Hh * 4);
    float* bc     = (float*)alloc(NFf * 4);

    hipMemsetAsync(degi,   0, (size_t)N * 4, stream);
    hipMemsetAsync(cursor, 0, (size_t)N * 4, stream);
    hipMemsetAsync(c_buf,  0, (size_t)N * Hh * 4, stream);

    const int b256n = (N + 255) / 256;
    const int b256e = (E + 255) / 256;
    const int nb16  = (N + 15) / 16;

    node_mask_k<<<b256n, 256, 0, stream>>>(xmask, mask, N);
    deg_count_k<<<b256e, 256, 0, stream>>>(edst, degi, E, N);
    dinv_k<<<b256n, 256, 0, stream>>>(degi, dinv, N);
    scan_k<<<1, 1024, 0, stream>>>(degi, rowptr, N);
    csr_fill_k<<<b256e, 256, 0, stream>>>(esrc, edst, dinv, rowptr, cursor, colsrc, wnorm, E, N);
    whhT_prep_k<<<(FH * Hh + 255) / 256, 256, 0, stream>>>(W_hh, WhhT);
    fuse_in_k<<<(Lz * FH + FH + 255) / 256, 256, 0, stream>>>(W_fc2, W_ih, b_fc2, b_ih, Wz, bz);
    fuse_gcn_k<<<(Hh * NFf + NFf + 255) / 256, 256, 0, stream>>>(W_gcn, W_fc3, b_gcn, b_fc3, WcT, bc);

    fc2_k<<<nb16, 128, 0, stream>>>(z, W_fc2, b_fc2, h_buf, N);
    xproj_k<<<nb16, 128, 0, stream>>>(z, Wz, bz, xproj, N);

    for (int t = 0; t < Tt; ++t)
        lstm_fused_k<<<nb16, 128, 0, stream>>>(xproj, WhhT, b_hh, h_buf, c_buf, mask, WcT, pw, t, N);

    agg_out_k<<<(N + 3) / 4, 256, 0, stream>>>(pw, rowptr, colsrc, wnorm, dinv, bc, out, N);
}

// Round 6
// 488.123 us; speedup vs baseline: 3.1192x; 2.0554x over previous
//
#include <hip/hip_runtime.h>
#include <hip/hip_bf16.h>

#define Hh   128
#define FH   512
#define Lz   64
#define Tt   12
#define NFf  16

typedef __attribute__((ext_vector_type(8))) short short8;   // 8 bf16 = 4 VGPRs
typedef __attribute__((ext_vector_type(4))) float f32x4;

__device__ __forceinline__ float sigf(float x) { return 1.0f / (1.0f + __expf(-x)); }

// ---------------- graph prep ----------------

__global__ void node_mask_k(const unsigned char* __restrict__ xm, float* __restrict__ mask, int Nn)
{
    int n = blockIdx.x * 256 + threadIdx.x;
    if (n >= Nn) return;
    const unsigned int* p = (const unsigned int*)(xm + (size_t)n * 192);
    unsigned int o = 0;
#pragma unroll
    for (int i = 0; i < 48; ++i) o |= p[i];
    mask[n] = o ? 1.0f : 0.0f;
}

__global__ void deg_count_k(const int* __restrict__ dst, int* __restrict__ degi, int E, int Nn)
{
    int e = blockIdx.x * 256 + threadIdx.x;
    if (e >= E) return;
    int d = dst[e]; d = d < 0 ? 0 : (d >= Nn ? Nn - 1 : d);
    atomicAdd(&degi[d], 1);
}

__global__ void dinv_k(const int* __restrict__ degi, float* __restrict__ dinv, int Nn)
{
    int n = blockIdx.x * 256 + threadIdx.x;
    if (n >= Nn) return;
    dinv[n] = rsqrtf((float)(degi[n] + 1)); // +1 self loop
}

__global__ void scan_k(const int* __restrict__ degi, int* __restrict__ rowptr, int Nn)
{
    __shared__ int wsum[16];
    __shared__ int carry;
    int tid = threadIdx.x;           // 1024
    int lane = tid & 63, wid = tid >> 6;
    if (tid == 0) carry = 0;
    __syncthreads();
    for (int base = 0; base < Nn; base += 1024) {
        int i = base + tid;
        int v = (i < Nn) ? degi[i] : 0;
        int x = v;
#pragma unroll
        for (int off = 1; off < 64; off <<= 1) {
            int y = __shfl_up(x, off, 64);
            if (lane >= off) x += y;
        }
        if (lane == 63) wsum[wid] = x;
        __syncthreads();
        if (wid == 0) {
            int s = (lane < 16) ? wsum[lane] : 0;
#pragma unroll
            for (int off = 1; off < 16; off <<= 1) {
                int y = __shfl_up(s, off, 64);
                if (lane >= off) s += y;
            }
            if (lane < 16) wsum[lane] = s;
        }
        __syncthreads();
        int woff = (wid > 0) ? wsum[wid - 1] : 0;
        int inc = carry + woff + x;
        if (i < Nn) rowptr[i + 1] = inc;
        __syncthreads();
        if (tid == 1023) carry = inc;
        __syncthreads();
    }
    if (tid == 0) rowptr[0] = 0;
}

__global__ void csr_fill_k(const int* __restrict__ src, const int* __restrict__ dst,
                           const float* __restrict__ dinv, const int* __restrict__ rowptr,
                           int* __restrict__ cursor, int* __restrict__ colsrc,
                           float* __restrict__ wnorm, int E, int Nn)
{
    int e = blockIdx.x * 256 + threadIdx.x;
    if (e >= E) return;
    int s = src[e]; s = s < 0 ? 0 : (s >= Nn ? Nn - 1 : s);
    int d = dst[e]; d = d < 0 ? 0 : (d >= Nn ? Nn - 1 : d);
    int pos = rowptr[d] + atomicAdd(&cursor[d], 1);
    colsrc[pos] = s;
    wnorm[pos]  = dinv[s] * dinv[d];
}

// ---------------- weight prep ----------------

// Pack W_hh into MFMA B-fragment order, split bf16 (hi + lo).
// B[k][j] = W_hh[j][k].  Fragment chunk (ctile c, ktile kt): lane l elem e holds
// B[kt*32 + (l>>4)*8 + e][c*16 + (l&15)], stored contiguously 1KB per (c,kt).
__global__ void pack_whh_k(const float* __restrict__ Whh,
                           __hip_bfloat16* __restrict__ Bhi, __hip_bfloat16* __restrict__ Blo)
{
    int gid = blockIdx.x * 256 + threadIdx.x;     // 65536
    if (gid >= FH * Hh) return;
    int e  = gid & 7;
    int l  = (gid >> 3) & 63;
    int kt = (gid >> 9) & 3;
    int c  = gid >> 11;                            // [0,32)
    int k = kt * 32 + (l >> 4) * 8 + e;
    int j = c * 16 + (l & 15);
    float v = Whh[j * Hh + k];
    __hip_bfloat16 hi = __float2bfloat16(v);
    Bhi[gid] = hi;
    Blo[gid] = __float2bfloat16(v - __bfloat162float(hi));
}

// Wz[m][j] = sum_k Wf2[m][k] * Wih[j][k] ; bz[j] = sum_k bf2[k]*Wih[j][k] + bih[j]
__global__ void fuse_in_k(const float* __restrict__ Wf2, const float* __restrict__ Wih,
                          const float* __restrict__ bf2, const float* __restrict__ bih,
                          float* __restrict__ Wz, float* __restrict__ bz)
{
    int gid = blockIdx.x * 256 + threadIdx.x;
    if (gid < Lz * FH) {
        int m = gid >> 9, j = gid & 511;
        const float* a = Wf2 + m * Hh;
        const float* b = Wih + j * Hh;
        float s = 0.f;
#pragma unroll 4
        for (int k = 0; k < Hh; ++k) s += a[k] * b[k];
        Wz[m * FH + j] = s;
    } else if (gid < Lz * FH + FH) {
        int j = gid - Lz * FH;
        const float* b = Wih + j * Hh;
        float s = bih[j];
#pragma unroll 4
        for (int k = 0; k < Hh; ++k) s += bf2[k] * b[k];
        bz[j] = s;
    }
}

// WcT[f][k] = sum_h Wg[k][h] * W3[h][f]  ;  bc[f] = sum_h bg[h]*W3[h][f] + b3[f]
__global__ void fuse_gcn_k(const float* __restrict__ Wg, const float* __restrict__ W3,
                           const float* __restrict__ bg, const float* __restrict__ b3,
                           float* __restrict__ WcT, float* __restrict__ bc)
{
    int gid = blockIdx.x * 256 + threadIdx.x;
    if (gid < Hh * NFf) {
        int f = gid >> 7, k = gid & 127;
        const float* a = Wg + k * Hh;
        float s = 0.f;
#pragma unroll 4
        for (int h = 0; h < Hh; ++h) s += a[h] * W3[h * NFf + f];
        WcT[f * Hh + k] = s;
    } else if (gid < Hh * NFf + NFf) {
        int f = gid - Hh * NFf;
        float s = b3[f];
#pragma unroll 4
        for (int h = 0; h < Hh; ++h) s += bg[h] * W3[h * NFf + f];
        bc[f] = s;
    }
}

// ---------------- fc2: h0 = z @ W_fc2 + b (split bf16 out) ----------------

__global__ __launch_bounds__(128) void fc2_k(const float* __restrict__ z, const float* __restrict__ B,
                                             const float* __restrict__ bias,
                                             __hip_bfloat16* __restrict__ hbhi,
                                             __hip_bfloat16* __restrict__ hblo, int Nn)
{
    __shared__ float As[16][Lz];
    int n0 = blockIdx.x * 16;
    int tid = threadIdx.x; // 128
    for (int idx = tid; idx < 16 * Lz; idx += 128) {
        int r = idx >> 6, c = idx & 63;
        int n = n0 + r;
        As[r][c] = (n < Nn) ? z[(size_t)n * Lz + c] : 0.f;
    }
    __syncthreads();
    float acc[16];
#pragma unroll
    for (int i = 0; i < 16; ++i) acc[i] = 0.f;
    for (int k = 0; k < Lz; k += 2) {
        float w0 = B[k * Hh + tid];
        float w1 = B[(k + 1) * Hh + tid];
#pragma unroll
        for (int i = 0; i < 16; ++i) {
            float2 a = *(const float2*)&As[i][k];
            acc[i] += a.x * w0 + a.y * w1;
        }
    }
    float bb = bias[tid];
    for (int i = 0; i < 16; ++i) {
        int n = n0 + i;
        if (n < Nn) {
            float v = acc[i] + bb;
            __hip_bfloat16 hi = __float2bfloat16(v);
            size_t off = (size_t)n * Hh + tid;
            hbhi[off] = hi;
            hblo[off] = __float2bfloat16(v - __bfloat162float(hi));
        }
    }
}

// ---------------- xproj = z @ Wz + bz ----------------

__global__ __launch_bounds__(128) void xproj_k(const float* __restrict__ A, const float* __restrict__ B,
                                               const float* __restrict__ bias, float* __restrict__ C, int Nn)
{
    __shared__ float As[16][Lz];
    int n0 = blockIdx.x * 16;
    int j = threadIdx.x; // 128
    for (int idx = j; idx < 16 * Lz; idx += 128) {
        int r = idx >> 6, c = idx & 63;
        int n = n0 + r;
        As[r][c] = (n < Nn) ? A[(size_t)n * Lz + c] : 0.f;
    }
    __syncthreads();
    float acc[16][4];
#pragma unroll
    for (int r = 0; r < 16; ++r)
#pragma unroll
        for (int q = 0; q < 4; ++q) acc[r][q] = 0.f;
    for (int k0 = 0; k0 < Lz; k0 += 2) {
        float b0[4], b1[4];
#pragma unroll
        for (int q = 0; q < 4; ++q) {
            b0[q] = B[k0 * FH + q * 128 + j];
            b1[q] = B[(k0 + 1) * FH + q * 128 + j];
        }
#pragma unroll
        for (int r = 0; r < 16; ++r) {
            float2 a = *(const float2*)&As[r][k0];
#pragma unroll
            for (int q = 0; q < 4; ++q) acc[r][q] += a.x * b0[q] + a.y * b1[q];
        }
    }
    float bq[4];
#pragma unroll
    for (int q = 0; q < 4; ++q) bq[q] = bias[q * 128 + j];
    for (int r = 0; r < 16; ++r) {
        int n = n0 + r;
        if (n >= Nn) break;
#pragma unroll
        for (int q = 0; q < 4; ++q) C[(size_t)n * FH + q * 128 + j] = acc[r][q] + bq[q];
    }
}

// ---------------- MFMA LSTM step ----------------
// 256 threads = 4 waves, 16 rows/block. gates = h@Whh^T via split-bf16 MFMA:
// hi*Whi + lo*Whi + hi*Wlo  (residual ~1e-5 => f32-equivalent).
// Wave w owns hidden tiles m in {2w, 2w+1}; its 8 ctiles c = g*8+m carry the
// matching i/f/g/o columns, so pointwise is in-register via the C/D map
// col=lane&15, row=(lane>>4)*4+reg.

__global__ __launch_bounds__(256) void lstm_mfma_k(
    const float* __restrict__ xproj,
    const __hip_bfloat16* __restrict__ Bhi, const __hip_bfloat16* __restrict__ Blo,
    const float* __restrict__ bhh,
    __hip_bfloat16* __restrict__ hbhi, __hip_bfloat16* __restrict__ hblo,
    float* __restrict__ cbuf, const float* __restrict__ mask,
    const float* __restrict__ WcT, float* __restrict__ pw,
    int t, int Nn)
{
    __shared__ float hm_s[16][132];
    int tid = threadIdx.x;
    int l = tid & 63, wid = tid >> 6;
    int n0 = blockIdx.x * 16;

    // ---- A fragments: rows = lane&15, k = kt*32 + (lane>>4)*8 + e ----
    int arow = n0 + (l & 15); if (arow >= Nn) arow = Nn - 1;
    const short8* aphi = (const short8*)(hbhi + (size_t)arow * Hh + ((l >> 4) * 8));
    const short8* aplo = (const short8*)(hblo + (size_t)arow * Hh + ((l >> 4) * 8));
    short8 Ahi[4], Alo[4];
#pragma unroll
    for (int kt = 0; kt < 4; ++kt) {
        Ahi[kt] = aphi[kt * 4];    // 32 elems per kt = 4 short8
        Alo[kt] = aplo[kt * 4];
    }
    __syncthreads();   // all A loads complete before anyone overwrites hb

    int m0 = wid * 2;
    f32x4 acc[2][4];
#pragma unroll
    for (int mi = 0; mi < 2; ++mi)
#pragma unroll
        for (int g = 0; g < 4; ++g) acc[mi][g] = (f32x4){0.f, 0.f, 0.f, 0.f};

#pragma unroll
    for (int g = 0; g < 4; ++g) {
#pragma unroll
        for (int mi = 0; mi < 2; ++mi) {
            int c = g * 8 + m0 + mi;
            const short8* bhp = (const short8*)Bhi + (size_t)(c * 4) * 64 + l;
            const short8* blp = (const short8*)Blo + (size_t)(c * 4) * 64 + l;
            f32x4 a = acc[mi][g];
#pragma unroll
            for (int kt = 0; kt < 4; ++kt) {
                short8 bh = bhp[kt * 64];
                short8 bl = blp[kt * 64];
                a = __builtin_amdgcn_mfma_f32_16x16x32_bf16(Ahi[kt], bh, a, 0, 0, 0);
                a = __builtin_amdgcn_mfma_f32_16x16x32_bf16(Alo[kt], bh, a, 0, 0, 0);
                a = __builtin_amdgcn_mfma_f32_16x16x32_bf16(Ahi[kt], bl, a, 0, 0, 0);
            }
            acc[mi][g] = a;
        }
    }

    // ---- pointwise gates, state update, hm -> LDS ----
#pragma unroll
    for (int mi = 0; mi < 2; ++mi) {
        int j = (m0 + mi) * 16 + (l & 15);       // hidden col
        float bI = bhh[j], bF = bhh[128 + j], bG = bhh[256 + j], bO = bhh[384 + j];
#pragma unroll
        for (int r = 0; r < 4; ++r) {
            int i = (l >> 4) * 4 + r;
            int n = n0 + i;
            float hmv = 0.f;
            if (n < Nn) {
                const float* xp = xproj + (size_t)n * FH;
                float gi = acc[mi][0][r] + bI + xp[j];
                float gf = acc[mi][1][r] + bF + xp[128 + j];
                float gg = acc[mi][2][r] + bG + xp[256 + j];
                float go = acc[mi][3][r] + bO + xp[384 + j];
                size_t off = (size_t)n * Hh + j;
                float cn = sigf(gf) * cbuf[off] + sigf(gi) * tanhf(gg);
                float hn = sigf(go) * tanhf(cn);
                cbuf[off] = cn;
                __hip_bfloat16 hi16 = __float2bfloat16(hn);
                hbhi[off] = hi16;
                hblo[off] = __float2bfloat16(hn - __bfloat162float(hi16));
                hmv = hn * mask[n];
            }
            hm_s[i][j] = hmv;
        }
    }
    __syncthreads();

    // ---- pw[n][t][f] = hm . WcT[f] ----
    int r2 = tid >> 4, f = tid & 15;
    const float4* wf  = (const float4*)(WcT + f * Hh);
    const float4* hm4 = (const float4*)(&hm_s[r2][0]);
    float a = 0.f;
#pragma unroll
    for (int k4 = 0; k4 < 32; ++k4) {
        float4 av = hm4[k4];
        float4 bv = wf[k4];
        a += av.x * bv.x + av.y * bv.y + av.z * bv.z + av.w * bv.w;
    }
    int n = n0 + r2;
    if (n < Nn) pw[((size_t)n * Tt + t) * NFf + f] = a;
}

// ---------------- aggregate + bias -> out ----------------

__global__ __launch_bounds__(256) void agg_out_k(
    const float* __restrict__ pw, const int* __restrict__ rowptr,
    const int* __restrict__ colsrc, const float* __restrict__ wnorm,
    const float* __restrict__ dinv, const float* __restrict__ bc,
    float* __restrict__ out, int Nn)
{
    int lane = threadIdx.x & 63;
    int n = blockIdx.x * 4 + (threadIdx.x >> 6);
    if (n >= Nn) return;
    float dv = dinv[n];
    float sw = dv * dv;
    const float* pwn = pw + (size_t)n * 192;
    float a0 = pwn[lane] * sw;
    float a1 = pwn[64 + lane] * sw;
    float a2 = pwn[128 + lane] * sw;
    int s0 = rowptr[n], s1 = rowptr[n + 1];
    for (int e = s0; e < s1; ++e) {
        int s = colsrc[e];
        float w = wnorm[e];
        const float* ps = pw + (size_t)s * 192;
        a0 += ps[lane] * w;
        a1 += ps[64 + lane] * w;
        a2 += ps[128 + lane] * w;
    }
    float bcv = bc[lane & 15];
    float* on = out + (size_t)n * 192;
    on[lane]       = a0 + bcv;
    on[64 + lane]  = a1 + bcv;
    on[128 + lane] = a2 + bcv;
}

// ---------------- launcher ----------------

extern "C" void kernel_launch(void* const* d_in, const int* in_sizes, int n_in,
                              void* d_out, int out_size, void* d_ws, size_t ws_size,
                              hipStream_t stream)
{
    const float* z     = (const float*)d_in[0];
    const int*   edge  = (const int*)d_in[1];
    const unsigned char* xmask = (const unsigned char*)d_in[2];
    const float* W_fc2 = (const float*)d_in[3];
    const float* b_fc2 = (const float*)d_in[4];
    const float* W_ih  = (const float*)d_in[5];
    const float* W_hh  = (const float*)d_in[6];
    const float* b_ih  = (const float*)d_in[7];
    const float* b_hh  = (const float*)d_in[8];
    const float* W_gcn = (const float*)d_in[9];
    const float* b_gcn = (const float*)d_in[10];
    const float* W_fc3 = (const float*)d_in[11];
    const float* b_fc3 = (const float*)d_in[12];
    float* out = (float*)d_out;

    const int N = in_sizes[0] / Lz;   // 10000
    const int E = in_sizes[1] / 2;    // 160000
    const int* esrc = edge;
    const int* edst = edge + E;

    char* w = (char*)d_ws;
    auto alloc = [&](size_t bytes) { char* p = w; w += (bytes + 255) & ~(size_t)255; return p; };
    __hip_bfloat16* hbhi = (__hip_bfloat16*)alloc((size_t)N * Hh * 2);
    __hip_bfloat16* hblo = (__hip_bfloat16*)alloc((size_t)N * Hh * 2);
    float* c_buf  = (float*)alloc((size_t)N * Hh * 4);
    float* xproj  = (float*)alloc((size_t)N * FH * 4);
    float* pw     = (float*)alloc((size_t)N * Tt * NFf * 4);
    float* mask   = (float*)alloc((size_t)N * 4);
    float* dinv   = (float*)alloc((size_t)N * 4);
    int*   degi   = (int*)alloc((size_t)N * 4);
    int*   rowptr = (int*)alloc((size_t)(N + 1) * 4);
    int*   cursor = (int*)alloc((size_t)N * 4);
    int*   colsrc = (int*)alloc((size_t)E * 4);
    float* wnorm  = (float*)alloc((size_t)E * 4);
    __hip_bfloat16* Bphi = (__hip_bfloat16*)alloc((size_t)FH * Hh * 2);
    __hip_bfloat16* Bplo = (__hip_bfloat16*)alloc((size_t)FH * Hh * 2);
    float* Wz     = (float*)alloc((size_t)Lz * FH * 4);
    float* bz     = (float*)alloc(FH * 4);
    float* WcT    = (float*)alloc((size_t)NFf * Hh * 4);
    float* bc     = (float*)alloc(NFf * 4);

    hipMemsetAsync(degi,   0, (size_t)N * 4, stream);
    hipMemsetAsync(cursor, 0, (size_t)N * 4, stream);
    hipMemsetAsync(c_buf,  0, (size_t)N * Hh * 4, stream);

    const int b256n = (N + 255) / 256;
    const int b256e = (E + 255) / 256;
    const int nb16  = (N + 15) / 16;

    node_mask_k<<<b256n, 256, 0, stream>>>(xmask, mask, N);
    deg_count_k<<<b256e, 256, 0, stream>>>(edst, degi, E, N);
    dinv_k<<<b256n, 256, 0, stream>>>(degi, dinv, N);
    scan_k<<<1, 1024, 0, stream>>>(degi, rowptr, N);
    csr_fill_k<<<b256e, 256, 0, stream>>>(esrc, edst, dinv, rowptr, cursor, colsrc, wnorm, E, N);
    pack_whh_k<<<(FH * Hh + 255) / 256, 256, 0, stream>>>(W_hh, Bphi, Bplo);
    fuse_in_k<<<(Lz * FH + FH + 255) / 256, 256, 0, stream>>>(W_fc2, W_ih, b_fc2, b_ih, Wz, bz);
    fuse_gcn_k<<<(Hh * NFf + NFf + 255) / 256, 256, 0, stream>>>(W_gcn, W_fc3, b_gcn, b_fc3, WcT, bc);

    fc2_k<<<nb16, 128, 0, stream>>>(z, W_fc2, b_fc2, hbhi, hblo, N);
    xproj_k<<<nb16, 128, 0, stream>>>(z, Wz, bz, xproj, N);

    for (int t = 0; t < Tt; ++t)
        lstm_mfma_k<<<nb16, 256, 0, stream>>>(xproj, Bphi, Bplo, b_hh, hbhi, hblo,
                                              c_buf, mask, WcT, pw, t, N);

    agg_out_k<<<(N + 3) / 4, 256, 0, stream>>>(pw, rowptr, colsrc, wnorm, dinv, bc, out, N);
}